// Round 11
// baseline (246.986 us; speedup 1.0000x reference)
//
#include <hip/hip_runtime.h>
#include <hip/hip_bf16.h>
#include <math.h>

// Problem constants: S=8192, B=4, C=512, H=8, D=64
#define S_LEN 8192
#define BATCH 4
#define CDIM  512
#define HEADS 8
#define DDIM  64
#define MROWS (S_LEN * BATCH)   // 32768 rows; row m = s*BATCH + b; layout [S,B,C]
#define EPS_F 1e-6f

typedef __attribute__((ext_vector_type(8))) short     short8_t;
typedef __attribute__((ext_vector_type(4))) float     f32x4;
typedef unsigned short ushort_t;
typedef __attribute__((ext_vector_type(4))) unsigned short ushort4_t;
typedef __attribute__((ext_vector_type(8))) unsigned short ushort8_t;

static __device__ __forceinline__ ushort_t f2bf(float f) {
  __hip_bfloat16 h = __float2bfloat16(f);   // RNE
  return *(ushort_t*)&h;
}

// Async global->LDS, 16B per lane. LDS dest = wave-uniform base + lane*16.
static __device__ __forceinline__ void gl2lds16(const ushort_t* g, ushort_t* l) {
  __builtin_amdgcn_global_load_lds((const __attribute__((address_space(1))) void*)g,
                                   (__attribute__((address_space(3))) void*)l,
                                   16, 0, 0);
}

// ---------------------------------------------------------------------------
// Weights fp32 -> bf16, packed FRAGMENT-MAJOR:
//   frag (nfg 0..31, kf 0..15): 64 lanes x 8 shorts contiguous (1 KB).
//   lane = ((k>>3)&3)*16 + (n&15); elem j = k&7.
// ---------------------------------------------------------------------------
__global__ __launch_bounds__(256)
void cvtW_pack(const float* __restrict__ a, const float* __restrict__ b,
               const float* __restrict__ c, const float* __restrict__ d,
               ushort_t* __restrict__ oa, ushort_t* __restrict__ ob,
               ushort_t* __restrict__ oc, ushort_t* __restrict__ od) {
  const float* src = (blockIdx.y == 0) ? a : (blockIdx.y == 1) ? b :
                     (blockIdx.y == 2) ? c : d;
  ushort_t* dst    = (blockIdx.y == 0) ? oa : (blockIdx.y == 1) ? ob :
                     (blockIdx.y == 2) ? oc : od;
  const size_t i = ((size_t)blockIdx.x * 256 + threadIdx.x) * 8;
  const int n  = (int)(i >> 9);        // W row (output col)
  const int k0 = (int)(i & 511);       // 8 consecutive k
  const float4 x = *(const float4*)&src[i];
  const float4 y = *(const float4*)&src[i + 4];
  ushort8_t p;
  p[0] = f2bf(x.x); p[1] = f2bf(x.y); p[2] = f2bf(x.z); p[3] = f2bf(x.w);
  p[4] = f2bf(y.x); p[5] = f2bf(y.y); p[6] = f2bf(y.z); p[7] = f2bf(y.w);
  const int kf   = k0 >> 5;
  const int lane = ((k0 >> 3) & 3) * 16 + (n & 15);
  const int nfg  = n >> 4;
  *(ushort8_t*)&dst[(((size_t)nfg * 16 + kf) * 64 + lane) * 8] = p;
}

// ---------------------------------------------------------------------------
// Barrier-free GEMM main loop (A in LDS frag-packed; B frag-packed from
// global, 2-buffer prefetch; ZERO barriers). acc = 4mf x 8nf f32x4.
// ---------------------------------------------------------------------------
static __device__ __forceinline__
void nobar_mainloop(const ushort_t* __restrict__ alds,
                    const ushort_t* __restrict__ Wpk,
                    const int w, const int lane, f32x4 (&acc)[4][8]) {
  #pragma unroll
  for (int mi = 0; mi < 4; ++mi)
    #pragma unroll
    for (int nf = 0; nf < 8; ++nf)
      acc[mi][nf] = (f32x4){0.f, 0.f, 0.f, 0.f};

  short8_t a_[4], b0[8], b1[8];

  auto LB = [&](int kf, short8_t (&bb)[8]) {
    #pragma unroll
    for (int nf = 0; nf < 8; ++nf)
      bb[nf] = *(const short8_t*)&Wpk[(((size_t)(w * 8 + nf) * 16 + kf) * 64 + lane) * 8];
  };
  auto LA = [&](int kf) {
    #pragma unroll
    for (int mi = 0; mi < 4; ++mi)
      a_[mi] = *(const short8_t*)&alds[((kf * 4 + mi) * 64 + lane) * 8];
  };
  auto MF = [&](short8_t (&bb)[8]) {
    #pragma unroll
    for (int mi = 0; mi < 4; ++mi)
      #pragma unroll
      for (int nf = 0; nf < 8; ++nf)
        acc[mi][nf] = __builtin_amdgcn_mfma_f32_16x16x32_bf16(
            a_[mi], bb[nf], acc[mi][nf], 0, 0, 0);
  };

  LB(0, b0);
  LB(1, b1);
  #pragma unroll
  for (int kk = 0; kk < 16; ++kk) {
    LA(kk);
    if (kk & 1) {
      MF(b1);
      if (kk + 2 < 16) LB(kk + 2, b1);
    } else {
      MF(b0);
      if (kk + 2 < 16) LB(kk + 2, b0);
    }
  }
}

// ---------------------------------------------------------------------------
// Q/K/V projections, blockIdx.y = z in {q,k,v}.
// Staging: frag-gather. Wave w at step it stages frag (kf=it, mf=w): lane
// reads A row m0+w*16+(lane&15), k window it*32+(lane>>4)*8 (32B, nt,
// 64B-coalesced), cvt, ONE linear ds_write_b128 -> conflict-free.
// Epilogue: acc -> LDS (reused) -> linear short8 nt stores (coalesced 16B).
// ---------------------------------------------------------------------------
__global__ __launch_bounds__(256)
void proj3_nobar(const float* __restrict__ Xq, const float* __restrict__ Xk,
                 const float* __restrict__ Xv,
                 const ushort_t* __restrict__ Wqp, const ushort_t* __restrict__ Wkp,
                 const ushort_t* __restrict__ Wvp,
                 const float* __restrict__ bq, const float* __restrict__ bk,
                 const float* __restrict__ bv,
                 ushort_t* __restrict__ Yq, ushort_t* __restrict__ Yk,
                 ushort_t* __restrict__ Yv) {
  __shared__ __align__(16) ushort_t alds[32768];   // 64 frags x 1KB = 64KB
  const int z = blockIdx.y;
  const float*    X    = (z == 0) ? Xq : (z == 1) ? Xk : Xv;
  const ushort_t* Wpk  = (z == 0) ? Wqp : (z == 1) ? Wkp : Wvp;
  const float*    bias = (z == 0) ? bq : (z == 1) ? bk : bv;
  ushort_t*       Y    = (z == 0) ? Yq : (z == 1) ? Yk : Yv;
  const int t    = threadIdx.x;
  const int w    = t >> 6;
  const int lane = t & 63;
  const int r15  = lane & 15;
  const int kwin = lane >> 4;
  const int m0   = blockIdx.x * 64;

  // ---- stage A once: frag (kf=it, mf=w), conflict-free, nt loads ----
  const float* abase = X + (size_t)(m0 + w * 16 + r15) * CDIM + kwin * 8;
  #pragma unroll
  for (int it = 0; it < 16; ++it) {
    const f32x4 x0 = __builtin_nontemporal_load((const f32x4*)(abase + it * 32));
    const f32x4 x1 = __builtin_nontemporal_load((const f32x4*)(abase + it * 32 + 4));
    short8_t v;
    v[0] = (short)f2bf(x0[0]); v[1] = (short)f2bf(x0[1]);
    v[2] = (short)f2bf(x0[2]); v[3] = (short)f2bf(x0[3]);
    v[4] = (short)f2bf(x1[0]); v[5] = (short)f2bf(x1[1]);
    v[6] = (short)f2bf(x1[2]); v[7] = (short)f2bf(x1[3]);
    *(short8_t*)&alds[((it * 4 + w) * 64 + lane) * 8] = v;
  }
  __syncthreads();

  f32x4 acc[4][8];
  nobar_mainloop(alds, Wpk, w, lane, acc);

  // ---- epilogue: acc -> LDS [64][512] bf16, then coalesced nt stores ----
  __syncthreads();   // everyone done reading alds
  const bool act = (z < 2);
  #pragma unroll
  for (int nf = 0; nf < 8; ++nf) {
    const int col = w * 128 + nf * 16 + r15;
    const float bi = bias[col];
    #pragma unroll
    for (int mi = 0; mi < 4; ++mi)
      #pragma unroll
      for (int r = 0; r < 4; ++r) {
        const int row = mi * 16 + kwin * 4 + r;
        float vv = acc[mi][nf][r] + bi;
        if (act) vv = (vv > 0.f) ? (vv + 1.f) : expf(vv);
        alds[row * 512 + col] = f2bf(vv);
      }
  }
  __syncthreads();
  #pragma unroll
  for (int it = 0; it < 16; ++it) {
    const int u   = it * 256 + t;      // 16B packet, 0..4095
    const int row = u >> 6;
    const int c8  = (u & 63) * 8;
    const short8_t v = *(const short8_t*)&alds[u * 8];
    __builtin_nontemporal_store(v, (short8_t*)&Y[(size_t)(m0 + row) * CDIM + c8]);
  }
}

// ---------------------------------------------------------------------------
// Output projection: bf16 A staged via global_load_lds, fp32 out (64B
// coalesced already), nt stores on Y.
// ---------------------------------------------------------------------------
__global__ __launch_bounds__(256)
void outp_nobar(const ushort_t* __restrict__ A, const ushort_t* __restrict__ Wpk,
                const float* __restrict__ bias, float* __restrict__ Y) {
  __shared__ __align__(16) ushort_t alds[32768];
  const int t    = threadIdx.x;
  const int w    = t >> 6;
  const int lane = t & 63;
  const int m0   = blockIdx.x * 64;

  // 64 frags, wave stages 16: frag fid = w*16+j, kf=fid>>2, mf=fid&3
  #pragma unroll
  for (int j = 0; j < 16; ++j) {
    const int fid = w * 16 + j;
    const int kf = fid >> 2, mf = fid & 3;
    const ushort_t* ga = A +
        (size_t)(m0 + mf * 16 + (lane & 15)) * CDIM + kf * 32 + (lane >> 4) * 8;
    gl2lds16(ga, (ushort_t*)&alds[fid * 512]);
  }
  __syncthreads();   // drains vm+lgkm

  f32x4 acc[4][8];
  nobar_mainloop(alds, Wpk, w, lane, acc);

  #pragma unroll
  for (int nf = 0; nf < 8; ++nf) {
    const int col = w * 128 + nf * 16 + (lane & 15);
    const float bi = bias[col];
    #pragma unroll
    for (int mi = 0; mi < 4; ++mi) {
      #pragma unroll
      for (int r = 0; r < 4; ++r) {
        const int m = m0 + mi * 16 + (lane >> 4) * 4 + r;
        __builtin_nontemporal_store(acc[mi][nf][r] + bi,
                                    &Y[(size_t)m * CDIM + col]);
      }
    }
  }
}

// ---------------------------------------------------------------------------
// kv GEMM: per (b,h), kv[d][f] = sum_s k[s][d]*v[s][f], ksum[d] = sum_s k[s][d].
// Split-K: grid (32 bh, 16 chunks of 512 s). Reg-staged transpose into
// fragment-packed LDS (A = k^T, B = v); ksum via ones-B-fragment MFMA.
// ---------------------------------------------------------------------------
__global__ __launch_bounds__(256)
void gemm_kv(const ushort_t* __restrict__ Kb, const ushort_t* __restrict__ Vb,
             float* __restrict__ kvpart, float* __restrict__ ksumpart) {
  __shared__ __align__(16) ushort_t klds[8192];
  __shared__ __align__(16) ushort_t vlds[8192];
  const int bh    = blockIdx.x;
  const int chunk = blockIdx.y;
  const int b = bh >> 3, h = bh & 7;
  const int t = threadIdx.x;
  const int w = t >> 6;
  const int lane = t & 63;

  f32x4 acc[4];
  #pragma unroll
  for (int fg = 0; fg < 4; ++fg) acc[fg] = (f32x4){0.f, 0.f, 0.f, 0.f};
  f32x4 accs = (f32x4){0.f, 0.f, 0.f, 0.f};

  short8_t ones;
  #pragma unroll
  for (int i = 0; i < 8; ++i) ones[i] = (short)0x3F80;

  for (int round = 0; round < 4; ++round) {
    const int sbase = chunk * 512 + round * 128;
    __syncthreads();
    #pragma unroll
    for (int i = 0; i < 4; ++i) {
      const int idx  = i * 256 + t;
      const int sl   = idx >> 3;
      const int d8   = idx & 7;
      const size_t src = (size_t)((sbase + sl) * BATCH + b) * CDIM + h * DDIM + d8 * 8;
      const ushort8_t kp = *(const ushort8_t*)&Kb[src];
      const ushort8_t vp = *(const ushort8_t*)&Vb[src];
      const int sb  = sl >> 5;
      const int j   = sl & 7;
      const int lp0 = (d8 & 1) * 8 + ((sl >> 3) & 3) * 16;
      const int dg  = d8 >> 1;
      const int kbase = ((sb * 4 + dg) * 64 + lp0) * 8 + j;
      #pragma unroll
      for (int e = 0; e < 8; ++e) {
        klds[kbase + e * 8] = kp[e];
        vlds[kbase + e * 8] = vp[e];
      }
    }
    __syncthreads();
    #pragma unroll
    for (int sb = 0; sb < 4; ++sb) {
      const short8_t af = *(const short8_t*)&klds[((sb * 4 + w) * 64 + lane) * 8];
      accs = __builtin_amdgcn_mfma_f32_16x16x32_bf16(af, ones, accs, 0, 0, 0);
      #pragma unroll
      for (int fg = 0; fg < 4; ++fg) {
        const short8_t bf = *(const short8_t*)&vlds[((sb * 4 + fg) * 64 + lane) * 8];
        acc[fg] = __builtin_amdgcn_mfma_f32_16x16x32_bf16(af, bf, acc[fg], 0, 0, 0);
      }
    }
  }

  const size_t obase = ((size_t)bh * 16 + chunk) * 64;
  #pragma unroll
  for (int fg = 0; fg < 4; ++fg)
    #pragma unroll
    for (int r = 0; r < 4; ++r) {
      const int d = w * 16 + (lane >> 4) * 4 + r;
      kvpart[(obase + d) * 64 + fg * 16 + (lane & 15)] = acc[fg][r];
    }
  if ((lane & 15) == 0) {
    #pragma unroll
    for (int r = 0; r < 4; ++r)
      ksumpart[obase + w * 16 + (lane >> 4) * 4 + r] = accs[r];
  }
}

// ---------------------------------------------------------------------------
__global__ __launch_bounds__(256)
void kv_finish(const float* __restrict__ kvpart, const float* __restrict__ ksumpart,
               ushort_t* __restrict__ kvT) {
  const int bh = blockIdx.x;
  const int t  = threadIdx.x;
  for (int idx = t; idx < 4096; idx += 256) {
    const int d = idx >> 6, f = idx & 63;
    float s = 0.f;
    for (int c = 0; c < 16; ++c)
      s += kvpart[(((size_t)bh * 16 + c) * 64 + d) * 64 + f];
    kvT[((size_t)bh * 80 + f) * 64 + d] = f2bf(s);
  }
  if (t < 64) {
    float s = 0.f;
    for (int c = 0; c < 16; ++c)
      s += ksumpart[((size_t)bh * 16 + c) * 64 + t];
    kvT[((size_t)bh * 80 + 64) * 64 + t] = f2bf(s);
  }
  for (int i = t; i < 15 * 64; i += 256)
    kvT[((size_t)bh * 80 + 65) * 64 + i] = 0;
}

// ---------------------------------------------------------------------------
// qkv GEMM: y = (q @ kv) / (q . ksum + eps); B = kvT_pad [80][64], col 64 = denom.
// ---------------------------------------------------------------------------
__global__ __launch_bounds__(256)
void gemm_qkv(ushort_t* __restrict__ Qb, const ushort_t* __restrict__ kvT) {
  __shared__ __align__(16) ushort_t alds[8192];
  __shared__ __align__(16) ushort_t blds[5120];
  const int bh    = blockIdx.x;
  const int chunk = blockIdx.y;
  const int b = bh >> 3, h = bh & 7;
  const int t = threadIdx.x;
  const int w = t >> 6;
  const int lane = t & 63;
  const int lr = lane & 15;
  const int lk = (lane >> 4) * 8;

  #pragma unroll
  for (int i = 0; i < 4; ++i) {
    const int fidx = w * 4 + i;
    const int ks = fidx >> 3, fm = fidx & 7;
    const ushort_t* src = Qb +
        (size_t)((chunk * 128 + fm * 16 + lr) * BATCH + b) * CDIM +
        h * DDIM + ks * 32 + lk;
    gl2lds16(src, &alds[fidx * 512]);
  }
  for (int idx = w; idx < 10; idx += 4) {
    const int ks = idx / 5, fg = idx % 5;
    const ushort_t* src = kvT + (size_t)(bh * 80 + fg * 16 + lr) * 64 + ks * 32 + lk;
    gl2lds16(src, &blds[idx * 512]);
  }
  __syncthreads();

  f32x4 acc[2][5];
  #pragma unroll
  for (int mi = 0; mi < 2; ++mi)
    #pragma unroll
    for (int fg = 0; fg < 5; ++fg)
      acc[mi][fg] = (f32x4){0.f, 0.f, 0.f, 0.f};

  #pragma unroll
  for (int ks = 0; ks < 2; ++ks) {
    short8_t af[2], bf[5];
    #pragma unroll
    for (int mi = 0; mi < 2; ++mi)
      af[mi] = *(const short8_t*)&alds[(ks * 8 + w * 2 + mi) * 512 + lane * 8];
    #pragma unroll
    for (int fg = 0; fg < 5; ++fg)
      bf[fg] = *(const short8_t*)&blds[(ks * 5 + fg) * 512 + lane * 8];
    #pragma unroll
    for (int mi = 0; mi < 2; ++mi)
      #pragma unroll
      for (int fg = 0; fg < 5; ++fg)
        acc[mi][fg] = __builtin_amdgcn_mfma_f32_16x16x32_bf16(
            af[mi], bf[fg], acc[mi][fg], 0, 0, 0);
  }

  #pragma unroll
  for (int mi = 0; mi < 2; ++mi) {
    #pragma unroll
    for (int r = 0; r < 4; ++r) {
      const float dv  = __shfl(acc[mi][4][r], lane & 48);
      const float inv = 1.f / (dv + EPS_F);
      const int s = chunk * 128 + w * 32 + mi * 16 + (lane >> 4) * 4 + r;
      const size_t rowb = (size_t)(s * BATCH + b) * CDIM + h * DDIM;
      #pragma unroll
      for (int fg = 0; fg < 4; ++fg)
        Qb[rowb + fg * 16 + lr] = f2bf(acc[mi][fg][r] * inv);
    }
  }
}

// ---------------------------------------------------------------------------
extern "C" void kernel_launch(void* const* d_in, const int* in_sizes, int n_in,
                              void* d_out, int out_size, void* d_ws, size_t ws_size,
                              hipStream_t stream) {
  const float* q_in = (const float*)d_in[0];
  const float* k_in = (const float*)d_in[1];
  const float* v_in = (const float*)d_in[2];
  const float* Wq   = (const float*)d_in[3];
  const float* bq   = (const float*)d_in[4];
  const float* Wk   = (const float*)d_in[5];
  const float* bk   = (const float*)d_in[6];
  const float* Wv   = (const float*)d_in[7];
  const float* bv   = (const float*)d_in[8];
  const float* Wp   = (const float*)d_in[9];
  const float* bp   = (const float*)d_in[10];
  float* out = (float*)d_out;

  const size_t NTOK = (size_t)MROWS * CDIM;      // 16,777,216 elems
  const size_t NW   = (size_t)CDIM * CDIM;       // 262,144
  ushort_t* Wqp    = (ushort_t*)d_ws;            // fragment-packed bf16 weights
  ushort_t* Wkp    = Wqp + NW;
  ushort_t* Wvp    = Wkp + NW;
  ushort_t* Wpp    = Wvp + NW;
  ushort_t* qbuf   = Wpp + NW;
  ushort_t* kbuf   = qbuf + NTOK;
  ushort_t* vbuf   = kbuf + NTOK;
  ushort_t* kvT    = vbuf + NTOK;                           // 32*80*64
  float* kvpart    = (float*)(kvT + (size_t)32 * 80 * 64);  // 512*64*64
  float* ksumpart  = kvpart + (size_t)512 * 64 * 64;        // 512*64

  const dim3 blk(256);

  // 1) Weights fp32 -> bf16, fragment-packed
  cvtW_pack<<<dim3(128, 4), blk, 0, stream>>>(Wq, Wk, Wv, Wp,
                                              Wqp, Wkp, Wvp, Wpp);

  // 2) Q/K/V projections: barrier-free main loop, conflict-free staging,
  //    nt streams (A in, Y out) to keep packed W hot in per-XCD L2
  proj3_nobar<<<dim3(MROWS / 64, 3), blk, 0, stream>>>(
      q_in, k_in, v_in, Wqp, Wkp, Wvp, bq, bk, bv, qbuf, kbuf, vbuf);

  // 3) kv = sum_s k^T v (+ ksum via ones-MFMA), split-K then finish
  gemm_kv<<<dim3(32, 16), blk, 0, stream>>>(kbuf, vbuf, kvpart, ksumpart);
  kv_finish<<<dim3(32), blk, 0, stream>>>(kvpart, ksumpart, kvT);

  // 4) y = (q @ kv) / (q . ksum + eps), bf16 in place over q buffer
  gemm_qkv<<<dim3(32, 64), blk, 0, stream>>>(qbuf, kvT);

  // 5) Output projection: barrier-free, bf16 A via DMA -> fp32 d_out (nt)
  outp_nobar<<<dim3(MROWS / 64), blk, 0, stream>>>(qbuf, Wpp, bp, out);
}

// Round 12
// 241.486 us; speedup vs baseline: 1.0228x; 1.0228x over previous
//
#include <hip/hip_runtime.h>
#include <hip/hip_bf16.h>
#include <math.h>

// Problem constants: S=8192, B=4, C=512, H=8, D=64
#define S_LEN 8192
#define BATCH 4
#define CDIM  512
#define HEADS 8
#define DDIM  64
#define MROWS (S_LEN * BATCH)   // 32768 rows; row m = s*BATCH + b; layout [S,B,C]
#define EPS_F 1e-6f

typedef __attribute__((ext_vector_type(8))) short     short8_t;
typedef __attribute__((ext_vector_type(4))) float     f32x4;
typedef unsigned short ushort_t;
typedef __attribute__((ext_vector_type(8))) unsigned short ushort8_t;

static __device__ __forceinline__ ushort_t f2bf(float f) {
  __hip_bfloat16 h = __float2bfloat16(f);   // RNE
  return *(ushort_t*)&h;
}

// Async global->LDS, 16B per lane. LDS dest = wave-uniform base + lane*16;
// global src is per-lane.
static __device__ __forceinline__ void gl2lds16(const ushort_t* g, ushort_t* l) {
  __builtin_amdgcn_global_load_lds((const __attribute__((address_space(1))) void*)g,
                                   (__attribute__((address_space(3))) void*)l,
                                   16, 0, 0);
}

// ---------------------------------------------------------------------------
// Weights fp32 -> bf16, packed FRAGMENT-MAJOR (r9-verified):
//   frag (nfg 0..31, kfg 0..15): 64 lanes x 8 shorts contiguous (1 KB).
//   lane = ((k>>3)&3)*16 + (n&15); elem j = k&7.
// ---------------------------------------------------------------------------
__global__ __launch_bounds__(256)
void cvtW_pack(const float* __restrict__ a, const float* __restrict__ b,
               const float* __restrict__ c, const float* __restrict__ d,
               ushort_t* __restrict__ oa, ushort_t* __restrict__ ob,
               ushort_t* __restrict__ oc, ushort_t* __restrict__ od) {
  const float* src = (blockIdx.y == 0) ? a : (blockIdx.y == 1) ? b :
                     (blockIdx.y == 2) ? c : d;
  ushort_t* dst    = (blockIdx.y == 0) ? oa : (blockIdx.y == 1) ? ob :
                     (blockIdx.y == 2) ? oc : od;
  const size_t i = ((size_t)blockIdx.x * 256 + threadIdx.x) * 8;
  const int n  = (int)(i >> 9);        // W row (output col)
  const int k0 = (int)(i & 511);       // 8 consecutive k
  const float4 x = *(const float4*)&src[i];
  const float4 y = *(const float4*)&src[i + 4];
  ushort8_t p;
  p[0] = f2bf(x.x); p[1] = f2bf(x.y); p[2] = f2bf(x.z); p[3] = f2bf(x.w);
  p[4] = f2bf(y.x); p[5] = f2bf(y.y); p[6] = f2bf(y.z); p[7] = f2bf(y.w);
  const int kf   = k0 >> 5;
  const int lane = ((k0 >> 3) & 3) * 16 + (n & 15);
  const int nfg  = n >> 4;
  *(ushort8_t*)&dst[(((size_t)nfg * 16 + kf) * 64 + lane) * 8] = p;
}

// ---------------------------------------------------------------------------
// 256x256-tile 2-phase MFMA GEMM (m230-V0 structure):
//   Y[m][n] = act( sum_k A[m][k]*W[n][k] + bias[n] ),  K = 512, N = 512.
// 512 thr = 8 waves (2m x 4n); wave = 128x64 out = 8mf x 4nf frags; BK=64
// (2 kf), 8 K-steps, ONE __syncthreads per step (stage next ∥ compute cur).
// LDS (dynamic 128KB): A 2x32KB frag-packed + B 2x32KB frag-packed.
// A fp32 path: T14 reg-prefetch (one step early, nt) -> cvt -> linear
// conflict-free ds_write. A bf16 path: gl2lds16. B: packed weights gl2lds16
// (1KB contiguous per frag).
// ---------------------------------------------------------------------------
template<int AF32, int OUTF32>
static __device__ __forceinline__
void gemm256_body(const void* __restrict__ Av, const ushort_t* __restrict__ Wpk,
                  const float* __restrict__ bias, void* __restrict__ Yv,
                  const bool act, const int m0, const int n0, ushort_t* lds) {
  const int t    = threadIdx.x;        // 0..511
  const int w    = t >> 6;             // 0..7
  const int lane = t & 63;
  const int lr   = lane & 15;
  const int lk8  = (lane >> 4) * 8;
  const int wm   = (w >> 2) * 128;     // wave m-offset in tile
  const int wn   = (w & 3) * 64;       // wave n-offset in tile

  const float*    Xf = (const float*)Av;
  const ushort_t* Ah = (const ushort_t*)Av;

  ushort_t* A0 = lds;
  ushort_t* A1 = lds + 16384;
  ushort_t* B0 = lds + 32768;
  ushort_t* B1 = lds + 49152;

  // This wave stages frags fid = w*4+j (j=0..3) for both A and B.
  // A frag fid: mf_g = fid>>1, kf = fid&1; lane holds row mf_g*16+lr,
  //             k = kf*32 + lk8 (8 elems).
  f32x4 ar[4][2];   // A fp32 prefetch regs (data for the NEXT staged step)

  auto regloadA = [&](int kt) {
    #pragma unroll
    for (int j = 0; j < 4; ++j) {
      const int fid = w * 4 + j;
      const size_t g = (size_t)(m0 + (fid >> 1) * 16 + lr) * CDIM +
                       kt + (fid & 1) * 32 + lk8;
      ar[j][0] = __builtin_nontemporal_load((const f32x4*)&Xf[g]);
      ar[j][1] = __builtin_nontemporal_load((const f32x4*)&Xf[g + 4]);
    }
  };
  auto stageA_f32 = [&](ushort_t* Ab) {
    #pragma unroll
    for (int j = 0; j < 4; ++j) {
      const int fid = w * 4 + j;
      short8_t v;
      v[0] = (short)f2bf(ar[j][0][0]); v[1] = (short)f2bf(ar[j][0][1]);
      v[2] = (short)f2bf(ar[j][0][2]); v[3] = (short)f2bf(ar[j][0][3]);
      v[4] = (short)f2bf(ar[j][1][0]); v[5] = (short)f2bf(ar[j][1][1]);
      v[6] = (short)f2bf(ar[j][1][2]); v[7] = (short)f2bf(ar[j][1][3]);
      *(short8_t*)&lds[(Ab - lds) + (size_t)fid * 512 + lane * 8] = v;
    }
  };
  auto stageA_bf16 = [&](ushort_t* Ab, int kt) {
    #pragma unroll
    for (int j = 0; j < 4; ++j) {
      const int fid = w * 4 + j;
      const ushort_t* g = Ah + (size_t)(m0 + (fid >> 1) * 16 + lr) * CDIM +
                          kt + (fid & 1) * 32 + lk8;
      gl2lds16(g, &Ab[fid * 512]);
    }
  };
  auto stageB = [&](ushort_t* Bb, int kt) {
    #pragma unroll
    for (int j = 0; j < 4; ++j) {
      const int fid = w * 4 + j;
      const size_t idx = ((size_t)((n0 >> 4) + (fid >> 1)) * 16 +
                          (kt >> 5) + (fid & 1));
      gl2lds16(Wpk + idx * 512 + lane * 8, &Bb[fid * 512]);
    }
  };

  f32x4 acc[8][4];
  #pragma unroll
  for (int mf = 0; mf < 8; ++mf)
    #pragma unroll
    for (int nf = 0; nf < 4; ++nf)
      acc[mf][nf] = (f32x4){0.f, 0.f, 0.f, 0.f};

  auto compute = [&](const ushort_t* Ab, const ushort_t* Bb) {
    short8_t bfr[2][4];
    #pragma unroll
    for (int kf = 0; kf < 2; ++kf)
      #pragma unroll
      for (int nf = 0; nf < 4; ++nf) {
        const int fidb = ((wn >> 4) + nf) * 2 + kf;
        bfr[kf][nf] = *(const short8_t*)&Bb[fidb * 512 + lane * 8];
      }
    #pragma unroll
    for (int mf = 0; mf < 8; ++mf) {
      const int fa = ((wm >> 4) + mf) * 2;
      const short8_t a0 = *(const short8_t*)&Ab[(fa + 0) * 512 + lane * 8];
      const short8_t a1 = *(const short8_t*)&Ab[(fa + 1) * 512 + lane * 8];
      #pragma unroll
      for (int nf = 0; nf < 4; ++nf)
        acc[mf][nf] = __builtin_amdgcn_mfma_f32_16x16x32_bf16(
            a0, bfr[0][nf], acc[mf][nf], 0, 0, 0);
      #pragma unroll
      for (int nf = 0; nf < 4; ++nf)
        acc[mf][nf] = __builtin_amdgcn_mfma_f32_16x16x32_bf16(
            a1, bfr[1][nf], acc[mf][nf], 0, 0, 0);
    }
  };

  // ---- prologue ----
  if (AF32) {
    regloadA(0);
    stageA_f32(A0);
    stageB(B0, 0);
    regloadA(64);           // data for step 1
  } else {
    stageA_bf16(A0, 0);
    stageB(B0, 0);
  }
  __syncthreads();

  // ---- main loop: 8 K-steps, one barrier each ----
  #pragma unroll
  for (int ks = 0; ks < 8; ++ks) {
    ushort_t* curA = (ks & 1) ? A1 : A0;
    ushort_t* curB = (ks & 1) ? B1 : B0;
    ushort_t* nxtA = (ks & 1) ? A0 : A1;
    ushort_t* nxtB = (ks & 1) ? B0 : B1;
    if (ks < 7) {
      if (AF32) {
        stageA_f32(nxtA);                       // regs hold (ks+1) data
        if (ks + 2 < 8) regloadA((ks + 2) * 64);
      } else {
        stageA_bf16(nxtA, (ks + 1) * 64);
      }
      stageB(nxtB, (ks + 1) * 64);
    }
    compute(curA, curB);
    __syncthreads();
  }

  // ---- epilogue ----
  if (OUTF32) {
    float* Yf = (float*)Yv;
    #pragma unroll
    for (int nf = 0; nf < 4; ++nf) {
      const int col = n0 + wn + nf * 16 + lr;
      const float bi = bias[col];
      #pragma unroll
      for (int mf = 0; mf < 8; ++mf) {
        #pragma unroll
        for (int r = 0; r < 4; ++r) {
          const int m = m0 + wm + mf * 16 + (lane >> 4) * 4 + r;
          __builtin_nontemporal_store(acc[mf][nf][r] + bi,
                                      &Yf[(size_t)m * CDIM + col]);
        }
      }
    }
  } else {
    // acc -> LDS [256][256] bf16 (reuses all 128KB), then linear nt stores
    ushort_t* Yh = (ushort_t*)Yv;
    #pragma unroll
    for (int nf = 0; nf < 4; ++nf) {
      const int col = wn + nf * 16 + lr;
      const float bi = bias[n0 + col];
      #pragma unroll
      for (int mf = 0; mf < 8; ++mf) {
        #pragma unroll
        for (int r = 0; r < 4; ++r) {
          const int row = wm + mf * 16 + (lane >> 4) * 4 + r;
          float vv = acc[mf][nf][r] + bi;
          if (act) vv = (vv > 0.f) ? (vv + 1.f) : expf(vv);
          lds[row * 256 + col] = f2bf(vv);
        }
      }
    }
    __syncthreads();
    #pragma unroll
    for (int it = 0; it < 16; ++it) {
      const int u   = it * 512 + t;      // 16B packet, 0..8191
      const int row = u >> 5;
      const int c8  = (u & 31) * 8;
      const short8_t v = *(const short8_t*)&lds[u * 8];
      __builtin_nontemporal_store(
          v, (short8_t*)&Yh[(size_t)(m0 + row) * CDIM + n0 + c8]);
    }
  }
}

// Q/K/V projections fused: blockIdx = (n-tile, m-tile, z)
__global__ __launch_bounds__(512)
void proj3_256(const float* __restrict__ Xq, const float* __restrict__ Xk,
               const float* __restrict__ Xv,
               const ushort_t* __restrict__ Wqp, const ushort_t* __restrict__ Wkp,
               const ushort_t* __restrict__ Wvp,
               const float* __restrict__ bq, const float* __restrict__ bk,
               const float* __restrict__ bv,
               ushort_t* __restrict__ Yq, ushort_t* __restrict__ Yk,
               ushort_t* __restrict__ Yv) {
  extern __shared__ ushort_t lds[];
  const int z = blockIdx.z;
  const float*    X    = (z == 0) ? Xq : (z == 1) ? Xk : Xv;
  const ushort_t* Wpk  = (z == 0) ? Wqp : (z == 1) ? Wkp : Wvp;
  const float*    bias = (z == 0) ? bq : (z == 1) ? bk : bv;
  ushort_t*       Y    = (z == 0) ? Yq : (z == 1) ? Yk : Yv;
  gemm256_body<1, 0>(X, Wpk, bias, Y, z < 2,
                     blockIdx.y * 256, blockIdx.x * 256, lds);
}

// Output projection: bf16 A, fp32 out
__global__ __launch_bounds__(512)
void outp_256(const ushort_t* __restrict__ A, const ushort_t* __restrict__ Wpk,
              const float* __restrict__ bias, float* __restrict__ Y) {
  extern __shared__ ushort_t lds[];
  gemm256_body<0, 1>(A, Wpk, bias, Y, false,
                     blockIdx.y * 256, blockIdx.x * 256, lds);
}

// ---------------------------------------------------------------------------
// kv GEMM: per (b,h), kv[d][f] = sum_s k[s][d]*v[s][f], ksum[d] = sum_s k[s][d].
// Split-K: grid (32 bh, 16 chunks of 512 s). Reg-staged transpose into
// fragment-packed LDS (A = k^T, B = v); ksum via ones-B-fragment MFMA.
// ---------------------------------------------------------------------------
__global__ __launch_bounds__(256)
void gemm_kv(const ushort_t* __restrict__ Kb, const ushort_t* __restrict__ Vb,
             float* __restrict__ kvpart, float* __restrict__ ksumpart) {
  __shared__ __align__(16) ushort_t klds[8192];
  __shared__ __align__(16) ushort_t vlds[8192];
  const int bh    = blockIdx.x;
  const int chunk = blockIdx.y;
  const int b = bh >> 3, h = bh & 7;
  const int t = threadIdx.x;
  const int w = t >> 6;
  const int lane = t & 63;

  f32x4 acc[4];
  #pragma unroll
  for (int fg = 0; fg < 4; ++fg) acc[fg] = (f32x4){0.f, 0.f, 0.f, 0.f};
  f32x4 accs = (f32x4){0.f, 0.f, 0.f, 0.f};

  short8_t ones;
  #pragma unroll
  for (int i = 0; i < 8; ++i) ones[i] = (short)0x3F80;

  for (int round = 0; round < 4; ++round) {
    const int sbase = chunk * 512 + round * 128;
    __syncthreads();
    #pragma unroll
    for (int i = 0; i < 4; ++i) {
      const int idx  = i * 256 + t;
      const int sl   = idx >> 3;
      const int d8   = idx & 7;
      const size_t src = (size_t)((sbase + sl) * BATCH + b) * CDIM + h * DDIM + d8 * 8;
      const ushort8_t kp = *(const ushort8_t*)&Kb[src];
      const ushort8_t vp = *(const ushort8_t*)&Vb[src];
      const int sb  = sl >> 5;
      const int j   = sl & 7;
      const int lp0 = (d8 & 1) * 8 + ((sl >> 3) & 3) * 16;
      const int dg  = d8 >> 1;
      const int kbase = ((sb * 4 + dg) * 64 + lp0) * 8 + j;
      #pragma unroll
      for (int e = 0; e < 8; ++e) {
        klds[kbase + e * 8] = kp[e];
        vlds[kbase + e * 8] = vp[e];
      }
    }
    __syncthreads();
    #pragma unroll
    for (int sb = 0; sb < 4; ++sb) {
      const short8_t af = *(const short8_t*)&klds[((sb * 4 + w) * 64 + lane) * 8];
      accs = __builtin_amdgcn_mfma_f32_16x16x32_bf16(af, ones, accs, 0, 0, 0);
      #pragma unroll
      for (int fg = 0; fg < 4; ++fg) {
        const short8_t bf = *(const short8_t*)&vlds[((sb * 4 + fg) * 64 + lane) * 8];
        acc[fg] = __builtin_amdgcn_mfma_f32_16x16x32_bf16(af, bf, acc[fg], 0, 0, 0);
      }
    }
  }

  const size_t obase = ((size_t)bh * 16 + chunk) * 64;
  #pragma unroll
  for (int fg = 0; fg < 4; ++fg)
    #pragma unroll
    for (int r = 0; r < 4; ++r) {
      const int d = w * 16 + (lane >> 4) * 4 + r;
      kvpart[(obase + d) * 64 + fg * 16 + (lane & 15)] = acc[fg][r];
    }
  if ((lane & 15) == 0) {
    #pragma unroll
    for (int r = 0; r < 4; ++r)
      ksumpart[obase + w * 16 + (lane >> 4) * 4 + r] = accs[r];
  }
}

// ---------------------------------------------------------------------------
__global__ __launch_bounds__(256)
void kv_finish(const float* __restrict__ kvpart, const float* __restrict__ ksumpart,
               ushort_t* __restrict__ kvT) {
  const int bh = blockIdx.x;
  const int t  = threadIdx.x;
  for (int idx = t; idx < 4096; idx += 256) {
    const int d = idx >> 6, f = idx & 63;
    float s = 0.f;
    for (int c = 0; c < 16; ++c)
      s += kvpart[(((size_t)bh * 16 + c) * 64 + d) * 64 + f];
    kvT[((size_t)bh * 80 + f) * 64 + d] = f2bf(s);
  }
  if (t < 64) {
    float s = 0.f;
    for (int c = 0; c < 16; ++c)
      s += ksumpart[((size_t)bh * 16 + c) * 64 + t];
    kvT[((size_t)bh * 80 + 64) * 64 + t] = f2bf(s);
  }
  for (int i = t; i < 15 * 64; i += 256)
    kvT[((size_t)bh * 80 + 65) * 64 + i] = 0;
}

// ---------------------------------------------------------------------------
// qkv GEMM: y = (q @ kv) / (q . ksum + eps); B = kvT_pad [80][64], col 64 = denom.
// ---------------------------------------------------------------------------
__global__ __launch_bounds__(256)
void gemm_qkv(ushort_t* __restrict__ Qb, const ushort_t* __restrict__ kvT) {
  __shared__ __align__(16) ushort_t alds[8192];
  __shared__ __align__(16) ushort_t blds[5120];
  const int bh    = blockIdx.x;
  const int chunk = blockIdx.y;
  const int b = bh >> 3, h = bh & 7;
  const int t = threadIdx.x;
  const int w = t >> 6;
  const int lane = t & 63;
  const int lr = lane & 15;
  const int lk = (lane >> 4) * 8;

  #pragma unroll
  for (int i = 0; i < 4; ++i) {
    const int fidx = w * 4 + i;
    const int ks = fidx >> 3, fm = fidx & 7;
    const ushort_t* src = Qb +
        (size_t)((chunk * 128 + fm * 16 + lr) * BATCH + b) * CDIM +
        h * DDIM + ks * 32 + lk;
    gl2lds16(src, &alds[fidx * 512]);
  }
  for (int idx = w; idx < 10; idx += 4) {
    const int ks = idx / 5, fg = idx % 5;
    const ushort_t* src = kvT + (size_t)(bh * 80 + fg * 16 + lr) * 64 + ks * 32 + lk;
    gl2lds16(src, &blds[idx * 512]);
  }
  __syncthreads();

  f32x4 acc[2][5];
  #pragma unroll
  for (int mi = 0; mi < 2; ++mi)
    #pragma unroll
    for (int fg = 0; fg < 5; ++fg)
      acc[mi][fg] = (f32x4){0.f, 0.f, 0.f, 0.f};

  #pragma unroll
  for (int ks = 0; ks < 2; ++ks) {
    short8_t af[2], bf[5];
    #pragma unroll
    for (int mi = 0; mi < 2; ++mi)
      af[mi] = *(const short8_t*)&alds[(ks * 8 + w * 2 + mi) * 512 + lane * 8];
    #pragma unroll
    for (int fg = 0; fg < 5; ++fg)
      bf[fg] = *(const short8_t*)&blds[(ks * 5 + fg) * 512 + lane * 8];
    #pragma unroll
    for (int mi = 0; mi < 2; ++mi)
      #pragma unroll
      for (int fg = 0; fg < 5; ++fg)
        acc[mi][fg] = __builtin_amdgcn_mfma_f32_16x16x32_bf16(
            af[mi], bf[fg], acc[mi][fg], 0, 0, 0);
  }

  #pragma unroll
  for (int mi = 0; mi < 2; ++mi) {
    #pragma unroll
    for (int r = 0; r < 4; ++r) {
      const float dv  = __shfl(acc[mi][4][r], lane & 48);
      const float inv = 1.f / (dv + EPS_F);
      const int s = chunk * 128 + w * 32 + mi * 16 + (lane >> 4) * 4 + r;
      const size_t rowb = (size_t)(s * BATCH + b) * CDIM + h * DDIM;
      #pragma unroll
      for (int fg = 0; fg < 4; ++fg)
        Qb[rowb + fg * 16 + lr] = f2bf(acc[mi][fg][r] * inv);
    }
  }
}

// ---------------------------------------------------------------------------
extern "C" void kernel_launch(void* const* d_in, const int* in_sizes, int n_in,
                              void* d_out, int out_size, void* d_ws, size_t ws_size,
                              hipStream_t stream) {
  const float* q_in = (const float*)d_in[0];
  const float* k_in = (const float*)d_in[1];
  const float* v_in = (const float*)d_in[2];
  const float* Wq   = (const float*)d_in[3];
  const float* bq   = (const float*)d_in[4];
  const float* Wk   = (const float*)d_in[5];
  const float* bk   = (const float*)d_in[6];
  const float* Wv   = (const float*)d_in[7];
  const float* bv   = (const float*)d_in[8];
  const float* Wp   = (const float*)d_in[9];
  const float* bp   = (const float*)d_in[10];
  float* out = (float*)d_out;

  const size_t NTOK = (size_t)MROWS * CDIM;      // 16,777,216 elems
  const size_t NW   = (size_t)CDIM * CDIM;       // 262,144
  ushort_t* Wqp    = (ushort_t*)d_ws;            // fragment-packed bf16 weights
  ushort_t* Wkp    = Wqp + NW;
  ushort_t* Wvp    = Wkp + NW;
  ushort_t* Wpp    = Wvp + NW;
  ushort_t* qbuf   = Wpp + NW;
  ushort_t* kbuf   = qbuf + NTOK;
  ushort_t* vbuf   = kbuf + NTOK;
  ushort_t* kvT    = vbuf + NTOK;                           // 32*80*64
  float* kvpart    = (float*)(kvT + (size_t)32 * 80 * 64);  // 512*64*64
  float* ksumpart  = kvpart + (size_t)512 * 64 * 64;        // 512*64

  const dim3 blk(256);
  const size_t LDSB = 131072;   // 128 KB dynamic LDS for the 256^2 GEMMs

  // 1) Weights fp32 -> bf16, fragment-packed
  cvtW_pack<<<dim3(128, 4), blk, 0, stream>>>(Wq, Wk, Wv, Wp,
                                              Wqp, Wkp, Wvp, Wpp);

  // 2) Q/K/V projections: 256^2-tile 2-phase (n-tile fastest for L2 pairing)
  proj3_256<<<dim3(CDIM / 256, MROWS / 256, 3), dim3(512), LDSB, stream>>>(
      q_in, k_in, v_in, Wqp, Wkp, Wvp, bq, bk, bv, qbuf, kbuf, vbuf);

  // 3) kv = sum_s k^T v (+ ksum via ones-MFMA), split-K then finish
  gemm_kv<<<dim3(32, 16), blk, 0, stream>>>(kbuf, vbuf, kvpart, ksumpart);
  kv_finish<<<dim3(32), blk, 0, stream>>>(kvpart, ksumpart, kvT);

  // 4) y = (q @ kv) / (q . ksum + eps), bf16 in place over q buffer
  gemm_qkv<<<dim3(32, 64), blk, 0, stream>>>(qbuf, kvT);

  // 5) Output projection: 256^2-tile, bf16 A via DMA -> fp32 d_out
  outp_256<<<dim3(CDIM / 256, MROWS / 256), dim3(512), LDSB, stream>>>(
      qbuf, Wpp, bp, out);
}

// Round 13
// 241.403 us; speedup vs baseline: 1.0231x; 1.0003x over previous
//
#include <hip/hip_runtime.h>
#include <hip/hip_bf16.h>
#include <math.h>

// Problem constants: S=8192, B=4, C=512, H=8, D=64
#define S_LEN 8192
#define BATCH 4
#define CDIM  512
#define HEADS 8
#define DDIM  64
#define MROWS (S_LEN * BATCH)   // 32768 rows; row m = s*BATCH + b; layout [S,B,C]
#define EPS_F 1e-6f

typedef __attribute__((ext_vector_type(8))) short     short8_t;
typedef __attribute__((ext_vector_type(4))) float     f32x4;
typedef unsigned short ushort_t;
typedef __attribute__((ext_vector_type(8))) unsigned short ushort8_t;

static __device__ __forceinline__ ushort_t f2bf(float f) {
  __hip_bfloat16 h = __float2bfloat16(f);   // RNE
  return *(ushort_t*)&h;
}

// Async global->LDS, 16B per lane. LDS dest = wave-uniform base + lane*16;
// global src is per-lane.
static __device__ __forceinline__ void gl2lds16(const ushort_t* g, ushort_t* l) {
  __builtin_amdgcn_global_load_lds((const __attribute__((address_space(1))) void*)g,
                                   (__attribute__((address_space(3))) void*)l,
                                   16, 0, 0);
}

// Counted waits (T4): allow the N just-issued vmem ops to stay in flight;
// everything older (the current buffer's staging) must be complete.
#define WAIT_VM12 asm volatile("s_waitcnt vmcnt(12) lgkmcnt(0)" ::: "memory")
#define WAIT_VM8  asm volatile("s_waitcnt vmcnt(8) lgkmcnt(0)"  ::: "memory")
#define WAIT_VM4  asm volatile("s_waitcnt vmcnt(4) lgkmcnt(0)"  ::: "memory")
#define WAIT_VM0  asm volatile("s_waitcnt vmcnt(0) lgkmcnt(0)"  ::: "memory")

// ---------------------------------------------------------------------------
// Weights fp32 -> bf16, packed FRAGMENT-MAJOR (r9-verified):
//   frag (nfg 0..31, kfg 0..15): 64 lanes x 8 shorts contiguous (1 KB).
//   lane = ((k>>3)&3)*16 + (n&15); elem j = k&7.
// ---------------------------------------------------------------------------
__global__ __launch_bounds__(256)
void cvtW_pack(const float* __restrict__ a, const float* __restrict__ b,
               const float* __restrict__ c, const float* __restrict__ d,
               ushort_t* __restrict__ oa, ushort_t* __restrict__ ob,
               ushort_t* __restrict__ oc, ushort_t* __restrict__ od) {
  const float* src = (blockIdx.y == 0) ? a : (blockIdx.y == 1) ? b :
                     (blockIdx.y == 2) ? c : d;
  ushort_t* dst    = (blockIdx.y == 0) ? oa : (blockIdx.y == 1) ? ob :
                     (blockIdx.y == 2) ? oc : od;
  const size_t i = ((size_t)blockIdx.x * 256 + threadIdx.x) * 8;
  const int n  = (int)(i >> 9);        // W row (output col)
  const int k0 = (int)(i & 511);       // 8 consecutive k
  const float4 x = *(const float4*)&src[i];
  const float4 y = *(const float4*)&src[i + 4];
  ushort8_t p;
  p[0] = f2bf(x.x); p[1] = f2bf(x.y); p[2] = f2bf(x.z); p[3] = f2bf(x.w);
  p[4] = f2bf(y.x); p[5] = f2bf(y.y); p[6] = f2bf(y.z); p[7] = f2bf(y.w);
  const int kf   = k0 >> 5;
  const int lane = ((k0 >> 3) & 3) * 16 + (n & 15);
  const int nfg  = n >> 4;
  *(ushort8_t*)&dst[(((size_t)nfg * 16 + kf) * 64 + lane) * 8] = p;
}

// ---------------------------------------------------------------------------
// 256x256-tile 2-phase MFMA GEMM with COUNTED-vmcnt sync (T3+T4+T5):
//   Y[m][n] = act( sum_k A[m][k]*W[n][k] + bias[n] ),  K = 512, N = 512.
// 512 thr = 8 waves (2m x 4n); wave = 128x64 out = 8mf x 4nf frags; BK=64,
// 8 K-steps. Per step: stage(next) -> counted wait (own prev-step loads
// only; prefetch stays in flight) -> s_barrier -> MFMA (setprio) ->
// s_barrier. No vmcnt(0) drain in the main loop.
// ---------------------------------------------------------------------------
template<int AF32, int OUTF32>
static __device__ __forceinline__
void gemm256_body(const void* __restrict__ Av, const ushort_t* __restrict__ Wpk,
                  const float* __restrict__ bias, void* __restrict__ Yv,
                  const bool act, const int m0, const int n0, ushort_t* lds) {
  const int t    = threadIdx.x;        // 0..511
  const int w    = t >> 6;             // 0..7
  const int lane = t & 63;
  const int lr   = lane & 15;
  const int lk8  = (lane >> 4) * 8;
  const int wm   = (w >> 2) * 128;     // wave m-offset in tile
  const int wn   = (w & 3) * 64;       // wave n-offset in tile

  const float*    Xf = (const float*)Av;
  const ushort_t* Ah = (const ushort_t*)Av;

  ushort_t* A0 = lds;
  ushort_t* A1 = lds + 16384;
  ushort_t* B0 = lds + 32768;
  ushort_t* B1 = lds + 49152;

  // This wave stages frags fid = w*4+j (j=0..3) for both A and B.
  f32x4 ar[4][2];   // A fp32 prefetch regs (data for the NEXT staged step)

  auto regloadA = [&](int kt) {
    #pragma unroll
    for (int j = 0; j < 4; ++j) {
      const int fid = w * 4 + j;
      const size_t g = (size_t)(m0 + (fid >> 1) * 16 + lr) * CDIM +
                       kt + (fid & 1) * 32 + lk8;
      ar[j][0] = __builtin_nontemporal_load((const f32x4*)&Xf[g]);
      ar[j][1] = __builtin_nontemporal_load((const f32x4*)&Xf[g + 4]);
    }
  };
  auto stageA_f32 = [&](ushort_t* Ab) {
    #pragma unroll
    for (int j = 0; j < 4; ++j) {
      const int fid = w * 4 + j;
      short8_t v;
      v[0] = (short)f2bf(ar[j][0][0]); v[1] = (short)f2bf(ar[j][0][1]);
      v[2] = (short)f2bf(ar[j][0][2]); v[3] = (short)f2bf(ar[j][0][3]);
      v[4] = (short)f2bf(ar[j][1][0]); v[5] = (short)f2bf(ar[j][1][1]);
      v[6] = (short)f2bf(ar[j][1][2]); v[7] = (short)f2bf(ar[j][1][3]);
      *(short8_t*)&Ab[(size_t)fid * 512 + lane * 8] = v;
    }
  };
  auto stageA_bf16 = [&](ushort_t* Ab, int kt) {
    #pragma unroll
    for (int j = 0; j < 4; ++j) {
      const int fid = w * 4 + j;
      const ushort_t* g = Ah + (size_t)(m0 + (fid >> 1) * 16 + lr) * CDIM +
                          kt + (fid & 1) * 32 + lk8;
      gl2lds16(g, &Ab[fid * 512]);
    }
  };
  auto stageB = [&](ushort_t* Bb, int kt) {
    #pragma unroll
    for (int j = 0; j < 4; ++j) {
      const int fid = w * 4 + j;
      const size_t idx = ((size_t)((n0 >> 4) + (fid >> 1)) * 16 +
                          (kt >> 5) + (fid & 1));
      gl2lds16(Wpk + idx * 512 + lane * 8, &Bb[fid * 512]);
    }
  };

  f32x4 acc[8][4];
  #pragma unroll
  for (int mf = 0; mf < 8; ++mf)
    #pragma unroll
    for (int nf = 0; nf < 4; ++nf)
      acc[mf][nf] = (f32x4){0.f, 0.f, 0.f, 0.f};

  auto compute = [&](const ushort_t* Ab, const ushort_t* Bb) {
    short8_t bfr[2][4];
    #pragma unroll
    for (int kf = 0; kf < 2; ++kf)
      #pragma unroll
      for (int nf = 0; nf < 4; ++nf) {
        const int fidb = ((wn >> 4) + nf) * 2 + kf;
        bfr[kf][nf] = *(const short8_t*)&Bb[fidb * 512 + lane * 8];
      }
    __builtin_amdgcn_s_setprio(1);
    #pragma unroll
    for (int mf = 0; mf < 8; ++mf) {
      const int fa = ((wm >> 4) + mf) * 2;
      const short8_t a0 = *(const short8_t*)&Ab[(fa + 0) * 512 + lane * 8];
      const short8_t a1 = *(const short8_t*)&Ab[(fa + 1) * 512 + lane * 8];
      #pragma unroll
      for (int nf = 0; nf < 4; ++nf)
        acc[mf][nf] = __builtin_amdgcn_mfma_f32_16x16x32_bf16(
            a0, bfr[0][nf], acc[mf][nf], 0, 0, 0);
      #pragma unroll
      for (int nf = 0; nf < 4; ++nf)
        acc[mf][nf] = __builtin_amdgcn_mfma_f32_16x16x32_bf16(
            a1, bfr[1][nf], acc[mf][nf], 0, 0, 0);
    }
    __builtin_amdgcn_s_setprio(0);
  };

  // ---- prologue: stage buf0; A-prefetch for step 1 stays in flight ----
  if (AF32) {
    regloadA(0);
    stageA_f32(A0);          // auto-waits its own loads, then ds_writes
    stageB(B0, 0);
    regloadA(64);            // data for step 1 (survives counted waits)
  } else {
    stageA_bf16(A0, 0);
    stageB(B0, 0);
  }

  // ---- main loop: 8 K-steps, counted waits, raw barriers ----
#define KSTEP(ks, WAITM)                                                   \
  do {                                                                     \
    ushort_t* curA = ((ks) & 1) ? A1 : A0;                                 \
    ushort_t* curB = ((ks) & 1) ? B1 : B0;                                 \
    ushort_t* nxtA = ((ks) & 1) ? A0 : A1;                                 \
    ushort_t* nxtB = ((ks) & 1) ? B0 : B1;                                 \
    if ((ks) < 7) {                                                        \
      if (AF32) {                                                          \
        stageA_f32(nxtA);                                                  \
        if ((ks) + 2 < 8) regloadA(((ks) + 2) * 64);                       \
      } else {                                                             \
        stageA_bf16(nxtA, ((ks) + 1) * 64);                                \
      }                                                                    \
      stageB(nxtB, ((ks) + 1) * 64);                                       \
    }                                                                      \
    WAITM;                                                                 \
    __builtin_amdgcn_s_barrier();                                          \
    __builtin_amdgcn_sched_barrier(0);                                     \
    compute(curA, curB);                                                   \
    __builtin_amdgcn_s_barrier();                                          \
  } while (0)

  if (AF32) {
    // per-step just-issued vmem: 8 A-nt + 4 B = 12 (steps 0..5); 4 (6); 0 (7)
    KSTEP(0, WAIT_VM12); KSTEP(1, WAIT_VM12); KSTEP(2, WAIT_VM12);
    KSTEP(3, WAIT_VM12); KSTEP(4, WAIT_VM12); KSTEP(5, WAIT_VM12);
    KSTEP(6, WAIT_VM4);  KSTEP(7, WAIT_VM0);
  } else {
    // per-step just-issued vmem: 4 A + 4 B = 8 (steps 0..6); 0 (7)
    KSTEP(0, WAIT_VM8); KSTEP(1, WAIT_VM8); KSTEP(2, WAIT_VM8);
    KSTEP(3, WAIT_VM8); KSTEP(4, WAIT_VM8); KSTEP(5, WAIT_VM8);
    KSTEP(6, WAIT_VM8); KSTEP(7, WAIT_VM0);
  }
#undef KSTEP

  // ---- epilogue ----
  if (OUTF32) {
    float* Yf = (float*)Yv;
    #pragma unroll
    for (int nf = 0; nf < 4; ++nf) {
      const int col = n0 + wn + nf * 16 + lr;
      const float bi = bias[col];
      #pragma unroll
      for (int mf = 0; mf < 8; ++mf) {
        #pragma unroll
        for (int r = 0; r < 4; ++r) {
          const int m = m0 + wm + mf * 16 + (lane >> 4) * 4 + r;
          __builtin_nontemporal_store(acc[mf][nf][r] + bi,
                                      &Yf[(size_t)m * CDIM + col]);
        }
      }
    }
  } else {
    // acc -> LDS [256][256] bf16 (reuses all 128KB), then linear nt stores
    ushort_t* Yh = (ushort_t*)Yv;
    #pragma unroll
    for (int nf = 0; nf < 4; ++nf) {
      const int col = wn + nf * 16 + lr;
      const float bi = bias[n0 + col];
      #pragma unroll
      for (int mf = 0; mf < 8; ++mf) {
        #pragma unroll
        for (int r = 0; r < 4; ++r) {
          const int row = wm + mf * 16 + (lane >> 4) * 4 + r;
          float vv = acc[mf][nf][r] + bi;
          if (act) vv = (vv > 0.f) ? (vv + 1.f) : expf(vv);
          lds[row * 256 + col] = f2bf(vv);
        }
      }
    }
    __syncthreads();
    #pragma unroll
    for (int it = 0; it < 16; ++it) {
      const int u   = it * 512 + t;      // 16B packet, 0..8191
      const int row = u >> 5;
      const int c8  = (u & 31) * 8;
      const short8_t v = *(const short8_t*)&lds[u * 8];
      __builtin_nontemporal_store(
          v, (short8_t*)&Yh[(size_t)(m0 + row) * CDIM + n0 + c8]);
    }
  }
}

// Q/K/V projections fused: blockIdx = (n-tile, m-tile, z)
__global__ __launch_bounds__(512)
void proj3_256(const float* __restrict__ Xq, const float* __restrict__ Xk,
               const float* __restrict__ Xv,
               const ushort_t* __restrict__ Wqp, const ushort_t* __restrict__ Wkp,
               const ushort_t* __restrict__ Wvp,
               const float* __restrict__ bq, const float* __restrict__ bk,
               const float* __restrict__ bv,
               ushort_t* __restrict__ Yq, ushort_t* __restrict__ Yk,
               ushort_t* __restrict__ Yv) {
  extern __shared__ ushort_t lds[];
  const int z = blockIdx.z;
  const float*    X    = (z == 0) ? Xq : (z == 1) ? Xk : Xv;
  const ushort_t* Wpk  = (z == 0) ? Wqp : (z == 1) ? Wkp : Wvp;
  const float*    bias = (z == 0) ? bq : (z == 1) ? bk : bv;
  ushort_t*       Y    = (z == 0) ? Yq : (z == 1) ? Yk : Yv;
  gemm256_body<1, 0>(X, Wpk, bias, Y, z < 2,
                     blockIdx.y * 256, blockIdx.x * 256, lds);
}

// Output projection: bf16 A, fp32 out
__global__ __launch_bounds__(512)
void outp_256(const ushort_t* __restrict__ A, const ushort_t* __restrict__ Wpk,
              const float* __restrict__ bias, float* __restrict__ Y) {
  extern __shared__ ushort_t lds[];
  gemm256_body<0, 1>(A, Wpk, bias, Y, false,
                     blockIdx.y * 256, blockIdx.x * 256, lds);
}

// ---------------------------------------------------------------------------
// kv GEMM: per (b,h), kv[d][f] = sum_s k[s][d]*v[s][f], ksum[d] = sum_s k[s][d].
// Split-K: grid (32 bh, 16 chunks of 512 s). Reg-staged transpose into
// fragment-packed LDS (A = k^T, B = v); ksum via ones-B-fragment MFMA.
// ---------------------------------------------------------------------------
__global__ __launch_bounds__(256)
void gemm_kv(const ushort_t* __restrict__ Kb, const ushort_t* __restrict__ Vb,
             float* __restrict__ kvpart, float* __restrict__ ksumpart) {
  __shared__ __align__(16) ushort_t klds[8192];
  __shared__ __align__(16) ushort_t vlds[8192];
  const int bh    = blockIdx.x;
  const int chunk = blockIdx.y;
  const int b = bh >> 3, h = bh & 7;
  const int t = threadIdx.x;
  const int w = t >> 6;
  const int lane = t & 63;

  f32x4 acc[4];
  #pragma unroll
  for (int fg = 0; fg < 4; ++fg) acc[fg] = (f32x4){0.f, 0.f, 0.f, 0.f};
  f32x4 accs = (f32x4){0.f, 0.f, 0.f, 0.f};

  short8_t ones;
  #pragma unroll
  for (int i = 0; i < 8; ++i) ones[i] = (short)0x3F80;

  for (int round = 0; round < 4; ++round) {
    const int sbase = chunk * 512 + round * 128;
    __syncthreads();
    #pragma unroll
    for (int i = 0; i < 4; ++i) {
      const int idx  = i * 256 + t;
      const int sl   = idx >> 3;
      const int d8   = idx & 7;
      const size_t src = (size_t)((sbase + sl) * BATCH + b) * CDIM + h * DDIM + d8 * 8;
      const ushort8_t kp = *(const ushort8_t*)&Kb[src];
      const ushort8_t vp = *(const ushort8_t*)&Vb[src];
      const int sb  = sl >> 5;
      const int j   = sl & 7;
      const int lp0 = (d8 & 1) * 8 + ((sl >> 3) & 3) * 16;
      const int dg  = d8 >> 1;
      const int kbase = ((sb * 4 + dg) * 64 + lp0) * 8 + j;
      #pragma unroll
      for (int e = 0; e < 8; ++e) {
        klds[kbase + e * 8] = kp[e];
        vlds[kbase + e * 8] = vp[e];
      }
    }
    __syncthreads();
    #pragma unroll
    for (int sb = 0; sb < 4; ++sb) {
      const short8_t af = *(const short8_t*)&klds[((sb * 4 + w) * 64 + lane) * 8];
      accs = __builtin_amdgcn_mfma_f32_16x16x32_bf16(af, ones, accs, 0, 0, 0);
      #pragma unroll
      for (int fg = 0; fg < 4; ++fg) {
        const short8_t bf = *(const short8_t*)&vlds[((sb * 4 + fg) * 64 + lane) * 8];
        acc[fg] = __builtin_amdgcn_mfma_f32_16x16x32_bf16(af, bf, acc[fg], 0, 0, 0);
      }
    }
  }

  const size_t obase = ((size_t)bh * 16 + chunk) * 64;
  #pragma unroll
  for (int fg = 0; fg < 4; ++fg)
    #pragma unroll
    for (int r = 0; r < 4; ++r) {
      const int d = w * 16 + (lane >> 4) * 4 + r;
      kvpart[(obase + d) * 64 + fg * 16 + (lane & 15)] = acc[fg][r];
    }
  if ((lane & 15) == 0) {
    #pragma unroll
    for (int r = 0; r < 4; ++r)
      ksumpart[obase + w * 16 + (lane >> 4) * 4 + r] = accs[r];
  }
}

// ---------------------------------------------------------------------------
__global__ __launch_bounds__(256)
void kv_finish(const float* __restrict__ kvpart, const float* __restrict__ ksumpart,
               ushort_t* __restrict__ kvT) {
  const int bh = blockIdx.x;
  const int t  = threadIdx.x;
  for (int idx = t; idx < 4096; idx += 256) {
    const int d = idx >> 6, f = idx & 63;
    float s = 0.f;
    for (int c = 0; c < 16; ++c)
      s += kvpart[(((size_t)bh * 16 + c) * 64 + d) * 64 + f];
    kvT[((size_t)bh * 80 + f) * 64 + d] = f2bf(s);
  }
  if (t < 64) {
    float s = 0.f;
    for (int c = 0; c < 16; ++c)
      s += ksumpart[((size_t)bh * 16 + c) * 64 + t];
    kvT[((size_t)bh * 80 + 64) * 64 + t] = f2bf(s);
  }
  for (int i = t; i < 15 * 64; i += 256)
    kvT[((size_t)bh * 80 + 65) * 64 + i] = 0;
}

// ---------------------------------------------------------------------------
// qkv GEMM: y = (q @ kv) / (q . ksum + eps); B = kvT_pad [80][64], col 64 = denom.
// ---------------------------------------------------------------------------
__global__ __launch_bounds__(256)
void gemm_qkv(ushort_t* __restrict__ Qb, const ushort_t* __restrict__ kvT) {
  __shared__ __align__(16) ushort_t alds[8192];
  __shared__ __align__(16) ushort_t blds[5120];
  const int bh    = blockIdx.x;
  const int chunk = blockIdx.y;
  const int b = bh >> 3, h = bh & 7;
  const int t = threadIdx.x;
  const int w = t >> 6;
  const int lane = t & 63;
  const int lr = lane & 15;
  const int lk = (lane >> 4) * 8;

  #pragma unroll
  for (int i = 0; i < 4; ++i) {
    const int fidx = w * 4 + i;
    const int ks = fidx >> 3, fm = fidx & 7;
    const ushort_t* src = Qb +
        (size_t)((chunk * 128 + fm * 16 + lr) * BATCH + b) * CDIM +
        h * DDIM + ks * 32 + lk;
    gl2lds16(src, &alds[fidx * 512]);
  }
  for (int idx = w; idx < 10; idx += 4) {
    const int ks = idx / 5, fg = idx % 5;
    const ushort_t* src = kvT + (size_t)(bh * 80 + fg * 16 + lr) * 64 + ks * 32 + lk;
    gl2lds16(src, &blds[idx * 512]);
  }
  __syncthreads();

  f32x4 acc[2][5];
  #pragma unroll
  for (int mi = 0; mi < 2; ++mi)
    #pragma unroll
    for (int fg = 0; fg < 5; ++fg)
      acc[mi][fg] = (f32x4){0.f, 0.f, 0.f, 0.f};

  #pragma unroll
  for (int ks = 0; ks < 2; ++ks) {
    short8_t af[2], bf[5];
    #pragma unroll
    for (int mi = 0; mi < 2; ++mi)
      af[mi] = *(const short8_t*)&alds[(ks * 8 + w * 2 + mi) * 512 + lane * 8];
    #pragma unroll
    for (int fg = 0; fg < 5; ++fg)
      bf[fg] = *(const short8_t*)&blds[(ks * 5 + fg) * 512 + lane * 8];
    #pragma unroll
    for (int mi = 0; mi < 2; ++mi)
      #pragma unroll
      for (int fg = 0; fg < 5; ++fg)
        acc[mi][fg] = __builtin_amdgcn_mfma_f32_16x16x32_bf16(
            af[mi], bf[fg], acc[mi][fg], 0, 0, 0);
  }

  #pragma unroll
  for (int mi = 0; mi < 2; ++mi) {
    #pragma unroll
    for (int r = 0; r < 4; ++r) {
      const float dv  = __shfl(acc[mi][4][r], lane & 48);
      const float inv = 1.f / (dv + EPS_F);
      const int s = chunk * 128 + w * 32 + mi * 16 + (lane >> 4) * 4 + r;
      const size_t rowb = (size_t)(s * BATCH + b) * CDIM + h * DDIM;
      #pragma unroll
      for (int fg = 0; fg < 4; ++fg)
        Qb[rowb + fg * 16 + lr] = f2bf(acc[mi][fg][r] * inv);
    }
  }
}

// ---------------------------------------------------------------------------
extern "C" void kernel_launch(void* const* d_in, const int* in_sizes, int n_in,
                              void* d_out, int out_size, void* d_ws, size_t ws_size,
                              hipStream_t stream) {
  const float* q_in = (const float*)d_in[0];
  const float* k_in = (const float*)d_in[1];
  const float* v_in = (const float*)d_in[2];
  const float* Wq   = (const float*)d_in[3];
  const float* bq   = (const float*)d_in[4];
  const float* Wk   = (const float*)d_in[5];
  const float* bk   = (const float*)d_in[6];
  const float* Wv   = (const float*)d_in[7];
  const float* bv   = (const float*)d_in[8];
  const float* Wp   = (const float*)d_in[9];
  const float* bp   = (const float*)d_in[10];
  float* out = (float*)d_out;

  const size_t NTOK = (size_t)MROWS * CDIM;      // 16,777,216 elems
  const size_t NW   = (size_t)CDIM * CDIM;       // 262,144
  ushort_t* Wqp    = (ushort_t*)d_ws;            // fragment-packed bf16 weights
  ushort_t* Wkp    = Wqp + NW;
  ushort_t* Wvp    = Wkp + NW;
  ushort_t* Wpp    = Wvp + NW;
  ushort_t* qbuf   = Wpp + NW;
  ushort_t* kbuf   = qbuf + NTOK;
  ushort_t* vbuf   = kbuf + NTOK;
  ushort_t* kvT    = vbuf + NTOK;                           // 32*80*64
  float* kvpart    = (float*)(kvT + (size_t)32 * 80 * 64);  // 512*64*64
  float* ksumpart  = kvpart + (size_t)512 * 64 * 64;        // 512*64

  const dim3 blk(256);
  const size_t LDSB = 131072;   // 128 KB dynamic LDS for the 256^2 GEMMs

  // 1) Weights fp32 -> bf16, fragment-packed
  cvtW_pack<<<dim3(128, 4), blk, 0, stream>>>(Wq, Wk, Wv, Wp,
                                              Wqp, Wkp, Wvp, Wpp);

  // 2) Q/K/V projections: 256^2-tile, counted-vmcnt pipeline
  proj3_256<<<dim3(CDIM / 256, MROWS / 256, 3), dim3(512), LDSB, stream>>>(
      q_in, k_in, v_in, Wqp, Wkp, Wvp, bq, bk, bv, qbuf, kbuf, vbuf);

  // 3) kv = sum_s k^T v (+ ksum via ones-MFMA), split-K then finish
  gemm_kv<<<dim3(32, 16), blk, 0, stream>>>(kbuf, vbuf, kvpart, ksumpart);
  kv_finish<<<dim3(32), blk, 0, stream>>>(kvpart, ksumpart, kvT);

  // 4) y = (q @ kv) / (q . ksum + eps), bf16 in place over q buffer
  gemm_qkv<<<dim3(32, 64), blk, 0, stream>>>(qbuf, kvT);

  // 5) Output projection: 256^2-tile counted-vmcnt, bf16 A -> fp32 d_out
  outp_256<<<dim3(CDIM / 256, MROWS / 256), dim3(512), LDSB, stream>>>(
      qbuf, Wpp, bp, out);
}